// Round 5
// baseline (122.982 us; speedup 1.0000x reference)
//
#include <hip/hip_runtime.h>

// 3-level Haar (db1) DWT on [B=256, L=131072] float32.
// Each thread processes 32 consecutive input elements (4 groups of 8):
//   -> cA3 x4, cD3 x4, cD2 x8, cD1 x16
// so every output stream stores as full f32x4 (16B/lane, dwordx4).
// Output row layout: [cA3 (L/8), cD3 (L/8), cD2 (L/4), cD1 (L/2)].

#define INV_SQRT2 0.70710678118654752440f

typedef float f32x4 __attribute__((ext_vector_type(4)));

__global__ void __launch_bounds__(256) dwt3_haar_kernel32(
    const float* __restrict__ x, float* __restrict__ out) {
    const int L   = 131072;
    const int T   = L >> 5;          // 4096 chunks of 32 elems per row
    const int gid = blockIdx.x * blockDim.x + threadIdx.x;

    const int row = gid >> 12;       // T = 2^12
    const int t   = gid & (T - 1);

    const int in_base = row * L + (t << 5);   // 128B-aligned

    float in[32];
    #pragma unroll
    for (int i = 0; i < 8; ++i) {
        const f32x4 v = *reinterpret_cast<const f32x4*>(x + in_base + 4 * i);
        in[4 * i + 0] = v.x; in[4 * i + 1] = v.y;
        in[4 * i + 2] = v.z; in[4 * i + 3] = v.w;
    }

    // Level 1: 16 pairs
    float cA1[16], cD1[16];
    #pragma unroll
    for (int i = 0; i < 16; ++i) {
        cA1[i] = (in[2 * i] + in[2 * i + 1]) * INV_SQRT2;
        cD1[i] = (in[2 * i] - in[2 * i + 1]) * INV_SQRT2;
    }

    // Level 2: 8 pairs
    float cA2[8], cD2[8];
    #pragma unroll
    for (int i = 0; i < 8; ++i) {
        cA2[i] = (cA1[2 * i] + cA1[2 * i + 1]) * INV_SQRT2;
        cD2[i] = (cA1[2 * i] - cA1[2 * i + 1]) * INV_SQRT2;
    }

    // Level 3: 4 pairs
    float cA3[4], cD3[4];
    #pragma unroll
    for (int i = 0; i < 4; ++i) {
        cA3[i] = (cA2[2 * i] + cA2[2 * i + 1]) * INV_SQRT2;
        cD3[i] = (cA2[2 * i] - cA2[2 * i + 1]) * INV_SQRT2;
    }

    const int row_out = row * L;

    f32x4 va3; va3.x = cA3[0]; va3.y = cA3[1]; va3.z = cA3[2]; va3.w = cA3[3];
    __builtin_nontemporal_store(va3,
        reinterpret_cast<f32x4*>(out + row_out + (t << 2)));

    f32x4 vd3; vd3.x = cD3[0]; vd3.y = cD3[1]; vd3.z = cD3[2]; vd3.w = cD3[3];
    __builtin_nontemporal_store(vd3,
        reinterpret_cast<f32x4*>(out + row_out + (L >> 3) + (t << 2)));

    float* d2p = out + row_out + (L >> 2) + (t << 3);
    #pragma unroll
    for (int i = 0; i < 2; ++i) {
        f32x4 v; v.x = cD2[4 * i]; v.y = cD2[4 * i + 1];
        v.z = cD2[4 * i + 2]; v.w = cD2[4 * i + 3];
        __builtin_nontemporal_store(v, reinterpret_cast<f32x4*>(d2p + 4 * i));
    }

    float* d1p = out + row_out + (L >> 1) + (t << 4);
    #pragma unroll
    for (int i = 0; i < 4; ++i) {
        f32x4 v; v.x = cD1[4 * i]; v.y = cD1[4 * i + 1];
        v.z = cD1[4 * i + 2]; v.w = cD1[4 * i + 3];
        __builtin_nontemporal_store(v, reinterpret_cast<f32x4*>(d1p + 4 * i));
    }
}

extern "C" void kernel_launch(void* const* d_in, const int* in_sizes, int n_in,
                              void* d_out, int out_size, void* d_ws, size_t ws_size,
                              hipStream_t stream) {
    const float* x = (const float*)d_in[0];
    float* out = (float*)d_out;

    const int total_threads = (256 * 131072) / 32;  // 1,048,576
    const int block = 256;
    const int grid = total_threads / block;         // 4096 blocks

    dwt3_haar_kernel32<<<grid, block, 0, stream>>>(x, out);
}

// Round 6
// 47.576 us; speedup vs baseline: 2.5850x; 2.5850x over previous
//
#include <hip/hip_runtime.h>

// 3-level Haar (db1) DWT on [B=256, L=131072] float32.
// Each thread processes 16 consecutive input elements (2 groups of 8):
//   -> cA3 x2, cD3 x2, cD2 x4, cD1 x8
// Output row layout: [cA3 (L/8), cD3 (L/8), cD2 (L/4), cD1 (L/2)].
// All stores nontemporal; every stream is lane-contiguous (8-16B/lane,
// dense 512-1024B segments per wave). NOTE (R5 lesson): widening per-lane
// store width past lane-contiguity (32 elems/thread) strides the lanes
// 64B apart -> partial-sector nt writes -> 2x HBM write amplification.

#define INV_SQRT2 0.70710678118654752440f

typedef float f32x2 __attribute__((ext_vector_type(2)));
typedef float f32x4 __attribute__((ext_vector_type(4)));

__global__ void __launch_bounds__(256) dwt3_haar_kernel16(
    const float* __restrict__ x, float* __restrict__ out) {
    const int L   = 131072;
    const int T   = L >> 4;          // 8192 chunks of 16 elems per row
    const int gid = blockIdx.x * blockDim.x + threadIdx.x;

    const int row = gid >> 13;       // T = 2^13
    const int t   = gid & (T - 1);   // chunk index within row

    const int in_base = row * L + (t << 4);   // 64B-aligned
    const f32x4 v0 = *reinterpret_cast<const f32x4*>(x + in_base);
    const f32x4 v1 = *reinterpret_cast<const f32x4*>(x + in_base + 4);
    const f32x4 v2 = *reinterpret_cast<const f32x4*>(x + in_base + 8);
    const f32x4 v3 = *reinterpret_cast<const f32x4*>(x + in_base + 12);

    // Level 1: 8 pairs
    const float cA1_0 = (v0.x + v0.y) * INV_SQRT2;
    const float cD1_0 = (v0.x - v0.y) * INV_SQRT2;
    const float cA1_1 = (v0.z + v0.w) * INV_SQRT2;
    const float cD1_1 = (v0.z - v0.w) * INV_SQRT2;
    const float cA1_2 = (v1.x + v1.y) * INV_SQRT2;
    const float cD1_2 = (v1.x - v1.y) * INV_SQRT2;
    const float cA1_3 = (v1.z + v1.w) * INV_SQRT2;
    const float cD1_3 = (v1.z - v1.w) * INV_SQRT2;
    const float cA1_4 = (v2.x + v2.y) * INV_SQRT2;
    const float cD1_4 = (v2.x - v2.y) * INV_SQRT2;
    const float cA1_5 = (v2.z + v2.w) * INV_SQRT2;
    const float cD1_5 = (v2.z - v2.w) * INV_SQRT2;
    const float cA1_6 = (v3.x + v3.y) * INV_SQRT2;
    const float cD1_6 = (v3.x - v3.y) * INV_SQRT2;
    const float cA1_7 = (v3.z + v3.w) * INV_SQRT2;
    const float cD1_7 = (v3.z - v3.w) * INV_SQRT2;

    // Level 2: 4 pairs
    const float cA2_0 = (cA1_0 + cA1_1) * INV_SQRT2;
    const float cD2_0 = (cA1_0 - cA1_1) * INV_SQRT2;
    const float cA2_1 = (cA1_2 + cA1_3) * INV_SQRT2;
    const float cD2_1 = (cA1_2 - cA1_3) * INV_SQRT2;
    const float cA2_2 = (cA1_4 + cA1_5) * INV_SQRT2;
    const float cD2_2 = (cA1_4 - cA1_5) * INV_SQRT2;
    const float cA2_3 = (cA1_6 + cA1_7) * INV_SQRT2;
    const float cD2_3 = (cA1_6 - cA1_7) * INV_SQRT2;

    // Level 3: 2 pairs
    const float cA3_0 = (cA2_0 + cA2_1) * INV_SQRT2;
    const float cD3_0 = (cA2_0 - cA2_1) * INV_SQRT2;
    const float cA3_1 = (cA2_2 + cA2_3) * INV_SQRT2;
    const float cD3_1 = (cA2_2 - cA2_3) * INV_SQRT2;

    const int row_out = row * L;

    f32x2 a3; a3.x = cA3_0; a3.y = cA3_1;
    __builtin_nontemporal_store(a3,
        reinterpret_cast<f32x2*>(out + row_out + (t << 1)));

    f32x2 d3; d3.x = cD3_0; d3.y = cD3_1;
    __builtin_nontemporal_store(d3,
        reinterpret_cast<f32x2*>(out + row_out + (L >> 3) + (t << 1)));

    f32x4 d2; d2.x = cD2_0; d2.y = cD2_1; d2.z = cD2_2; d2.w = cD2_3;
    __builtin_nontemporal_store(d2,
        reinterpret_cast<f32x4*>(out + row_out + (L >> 2) + (t << 2)));

    f32x4 d1a; d1a.x = cD1_0; d1a.y = cD1_1; d1a.z = cD1_2; d1a.w = cD1_3;
    f32x4 d1b; d1b.x = cD1_4; d1b.y = cD1_5; d1b.z = cD1_6; d1b.w = cD1_7;
    float* d1p = out + row_out + (L >> 1) + (t << 3);
    __builtin_nontemporal_store(d1a, reinterpret_cast<f32x4*>(d1p));
    __builtin_nontemporal_store(d1b, reinterpret_cast<f32x4*>(d1p + 4));
}

extern "C" void kernel_launch(void* const* d_in, const int* in_sizes, int n_in,
                              void* d_out, int out_size, void* d_ws, size_t ws_size,
                              hipStream_t stream) {
    const float* x = (const float*)d_in[0];
    float* out = (float*)d_out;

    const int total_threads = (256 * 131072) / 16;  // 2,097,152
    const int block = 256;
    const int grid = total_threads / block;         // 8192 blocks

    dwt3_haar_kernel16<<<grid, block, 0, stream>>>(x, out);
}